// Round 9
// baseline (1360.313 us; speedup 1.0000x reference)
//
#include <hip/hip_runtime.h>
#include <stdint.h>

// Problem constants: V=32000, B=64, T=256, D=512, H=1024
typedef unsigned short u16;
typedef unsigned int u32;
typedef __attribute__((ext_vector_type(4))) unsigned int u32x4;
typedef __attribute__((ext_vector_type(4))) float f32x4;
typedef __attribute__((ext_vector_type(8))) __bf16 bf16x8;

#define MFMA16(a, b, c) __builtin_amdgcn_mfma_f32_16x16x32_bf16((a), (b), (c), 0, 0, 0)

__device__ __forceinline__ u16 f2b(float f) {
  union { float f; unsigned u; } v; v.f = f;
  unsigned r = v.u + 0x7FFFu + ((v.u >> 16) & 1u);
  return (u16)(r >> 16);
}
__device__ __forceinline__ float b2f(u16 h) {
  union { unsigned u; float f; } v; v.u = ((unsigned)h) << 16;
  return v.f;
}
__device__ __forceinline__ float sigm(float x) { return 1.0f / (1.0f + __expf(-x)); }
__device__ __forceinline__ float tanh_fast(float x) {
  x = fminf(fmaxf(x, -15.0f), 15.0f);
  float t = __expf(2.0f * x);
  return (t - 1.0f) / (t + 1.0f);
}

// ---- LLC write-through / bypass helpers ----
template <int OFF>
__device__ __forceinline__ u32x4 ld16_sc(const void* p) {
  u32x4 r;
  asm volatile("global_load_dwordx4 %0, %1, off offset:%2 sc0 sc1"
               : "=v"(r) : "v"(p), "i"(OFF));
  return r;
}
__device__ __forceinline__ void st16_sc(void* p, u32x4 v) {
  asm volatile("global_store_dwordx4 %0, %1, off sc0 sc1"
               :: "v"(p), "v"(v) : "memory");
}
__device__ __forceinline__ void st4_sc(u32* p, u32 v) {
  asm volatile("global_store_dword %0, %1, off sc0 sc1"
               :: "v"(p), "v"(v) : "memory");
}
__device__ __forceinline__ u32 ld4_sc(const u32* p) {
  u32 r;
  asm volatile("global_load_dword %0, %1, off sc0 sc1\n\t"
               "s_waitcnt vmcnt(0)"
               : "=v"(r) : "v"(p) : "memory");
  return r;
}

// ---------------- prep kernels ----------------

// src[R][C] f32 -> dst[C][R] bf16 (B^T layout for GEMM / scan)
__global__ void transpose_cvt(const float* __restrict__ src, u16* __restrict__ dst,
                              int R, int C) {
  __shared__ float tile[32][33];
  const int c0 = blockIdx.x * 32, r0 = blockIdx.y * 32;
  const int tx = threadIdx.x, ty = threadIdx.y;
  for (int i = ty; i < 32; i += 8)
    tile[i][tx] = src[(size_t)(r0 + i) * C + (c0 + tx)];
  __syncthreads();
  for (int i = ty; i < 32; i += 8)
    dst[(size_t)(c0 + i) * R + (r0 + tx)] = f2b(tile[tx][i]);
}

// A_emb[m][0:512] = bf16(emb_table[y[m]][:]) ; m = b*T + t (y flat order)
__global__ void gather_cast(const int* __restrict__ y, const float* __restrict__ tab,
                            u16* __restrict__ A) {
  const int idx = blockIdx.x * 256 + threadIdx.x;
  const int m = idx >> 7;
  const int d0 = (idx & 127) << 2;
  const float4 v = *reinterpret_cast<const float4*>(tab + (size_t)y[m] * 512 + d0);
  ushort4 o;
  o.x = f2b(v.x); o.y = f2b(v.y); o.z = f2b(v.z); o.w = f2b(v.w);
  *reinterpret_cast<ushort4*>(A + (size_t)m * 512 + d0) = o;
}

// hidden[64][1024] f32 -> blocked slot 0: [w][g][ii][j], b=w*16+ii, n=g*16+j
__global__ void cast_h0_blocked(const float* __restrict__ h, u16* __restrict__ dst) {
  const int i = blockIdx.x * 256 + threadIdx.x;   // 65536 threads
  const int b = i >> 10, n = i & 1023;
  const int w = b >> 4, ii = b & 15, g = n >> 4, j = n & 15;
  dst[((size_t)w * 64 + g) * 256 + ii * 16 + j] = f2b(h[(size_t)b * 1024 + n]);
}

// ---------------- GEMM: C[m][n] = A[m][K] * Bt[n][K]^T + bias ----------------
// ALAYOUT 0: A row-major [M][K]. ALAYOUT 1: A = hbuf blocked
//   [slot][w][g'][16][16], row m -> slot (m>>6)+1, w=(m>>4)&3, ii=m&15.
template <int EPI, int ALAYOUT>
__global__ __launch_bounds__(256, 2) void gemm_bt(
    const u16* __restrict__ A, const u16* __restrict__ Bt,
    const float* __restrict__ bias, void* __restrict__ Cout,
    int M, int N, int K) {
  __shared__ u16 As[4096], Bs[4096];
  const int tid = threadIdx.x, lane = tid & 63, w = tid >> 6;
  const int wm = w >> 1, wn = w & 1, c = lane & 15, hq = lane >> 4;
  const int m0 = blockIdx.y * 128, n0 = blockIdx.x * 128;
  f32x4 acc[4][4] = {};

  const int slot0 = tid, slot1 = 256 + tid;
  const int r0_ = slot0 >> 2, ko0 = (slot0 & 3) << 3;
  const int r1_ = slot1 >> 2, ko1 = (slot1 & 3) << 3;

  for (int k0 = 0; k0 < K; k0 += 32) {
    u32x4 a0, a1;
    if (ALAYOUT == 0) {
      a0 = *(const u32x4*)(A + (size_t)(m0 + r0_) * K + k0 + ko0);
      a1 = *(const u32x4*)(A + (size_t)(m0 + r1_) * K + k0 + ko1);
    } else {
      const int ma = m0 + r0_, ka = k0 + ko0, mb = m0 + r1_, kb = k0 + ko1;
      a0 = *(const u32x4*)(A + ((((size_t)(ma >> 6) + 1) * 4 + ((ma >> 4) & 3)) * 64 +
                                (ka >> 4)) * 256 + (ma & 15) * 16 + (ka & 15));
      a1 = *(const u32x4*)(A + ((((size_t)(mb >> 6) + 1) * 4 + ((mb >> 4) & 3)) * 64 +
                                (kb >> 4)) * 256 + (mb & 15) * 16 + (kb & 15));
    }
    const u32x4 b0 = *(const u32x4*)(Bt + (size_t)(n0 + r0_) * K + k0 + ko0);
    const u32x4 b1 = *(const u32x4*)(Bt + (size_t)(n0 + r1_) * K + k0 + ko1);
    __syncthreads();
    *(u32x4*)(As + r0_ * 32 + ko0) = a0;
    *(u32x4*)(As + r1_ * 32 + ko1) = a1;
    *(u32x4*)(Bs + r0_ * 32 + ko0) = b0;
    *(u32x4*)(Bs + r1_ * 32 + ko1) = b1;
    __syncthreads();
    u32x4 af[4], bf[4];
#pragma unroll
    for (int i = 0; i < 4; ++i) {
      af[i] = *(const u32x4*)(As + (wm * 64 + i * 16 + c) * 32 + hq * 8);
      bf[i] = *(const u32x4*)(Bs + (wn * 64 + i * 16 + c) * 32 + hq * 8);
    }
#pragma unroll
    for (int mi = 0; mi < 4; ++mi)
#pragma unroll
      for (int ni = 0; ni < 4; ++ni)
        acc[mi][ni] = MFMA16(__builtin_bit_cast(bf16x8, af[mi]),
                             __builtin_bit_cast(bf16x8, bf[ni]), acc[mi][ni]);
  }

#pragma unroll
  for (int ni = 0; ni < 4; ++ni) {
    const int col = n0 + wn * 64 + ni * 16 + c;
    const float bv = bias[col];
#pragma unroll
    for (int mi = 0; mi < 4; ++mi) {
#pragma unroll
      for (int i = 0; i < 4; ++i) {
        const int m = m0 + wm * 64 + mi * 16 + hq * 4 + i;
        const float v = acc[mi][ni][i] + bv;
        if (EPI == 0) {
          const int dr = (m & 255) * 64 + (m >> 8);       // -> [t*64+b][3072]
          ((u16*)Cout)[(size_t)dr * N + col] = f2b(v);
        } else {
          const int dr = (m & 63) * 256 + (m >> 6);       // -> [b*256+t][512]
          ((float*)Cout)[(size_t)dr * N + col] = tanh_fast(v);
        }
      }
    }
  }
}

// ---------------- persistent GRU scan (64 WGs x 4 independent waves) --------
// WG g owns h-cols [g*16, g*16+16); wave w owns batch rows [w*16, w*16+16).
// Each wave is a COMPLETE per-step pipeline over full K=1024: poll 64 tags
// (one lane each) -> batch-load 32KB h slice (sc-bypass, staged vmcnt so MFMA
// overlaps the load tail) -> 96 MFMAs (3 gate tiles) -> gates in-wave ->
// LDS transpose -> 512B burst store -> drain -> tag publish. No k-split, no
// red exchange, no combine wave, ZERO barriers in the loop (whs is read-only
// after init; htile is per-wave). Row-group chains are fully independent.
// hbuf slots are FRESH per step (no WAR); tags are parity + monotonic.
__global__ __launch_bounds__(256, 1) void scan_kernel(
    const u16* __restrict__ wh_t,   // [3072][1024] bf16 (Wh^T)
    const float* __restrict__ bh,   // [3072]
    const float* __restrict__ h0,   // [64][1024] f32
    const u16* __restrict__ gx,     // [256*64][3072] bf16, t-major, incl. bx
    u16* __restrict__ hbuf,         // [257][4][64][256] bf16 blocked, fresh/step
    u32* __restrict__ tags) {       // [2][4][64][32] (128B-padded)
  __shared__ u16 whs[96 * 512];               // 96 KB Wh slice, fragment-ordered
  __shared__ __align__(16) u16 htile[4][256]; // per-wave transpose staging
  const int g = blockIdx.x;
  const int tid = threadIdx.x, lane = tid & 63, w = tid >> 6;
  const int c = lane & 15, hq = lane >> 4;
  const int gcol = g * 16 + c;
  const int row0 = w * 16;

  // stage Wh slice, fragment-ordered: fb = kk*3+ct, lane-linear 16B
  for (int fb = w; fb < 96; fb += 4) {
    const int kk = fb / 3, ct = fb % 3;
    const int n = ct * 1024 + g * 16 + c;
    const int k = kk * 32 + hq * 8;
    *(u32x4*)(whs + fb * 512 + lane * 8) =
        *(const u32x4*)(wh_t + (size_t)n * 1024 + k);
  }
  float bhv[3], hprev[4];
  u16 gxr[4][3];
#pragma unroll
  for (int ct = 0; ct < 3; ++ct) bhv[ct] = bh[ct * 1024 + gcol];
#pragma unroll
  for (int i = 0; i < 4; ++i)
    hprev[i] = h0[(size_t)(row0 + hq * 4 + i) * 1024 + gcol];
  {
    const u16* gp = gx + gcol;
#pragma unroll
    for (int i = 0; i < 4; ++i) {
      const int b = row0 + hq * 4 + i;
      gxr[i][0] = gp[(size_t)b * 3072];
      gxr[i][1] = gp[(size_t)b * 3072 + 1024];
      gxr[i][2] = gp[(size_t)b * 3072 + 2048];
    }
  }
  __syncthreads();  // whs ready (the only block-wide sync)

  for (int t = 0; t < 256; ++t) {
    // ---- poll all 64 producers of this row class (one tag per lane) ----
    if (t > 0) {
      const u32* tp = tags + ((size_t)(t & 1) * 4 + w) * (64 * 32) + lane * 32;
      while (__ballot(ld4_sc(tp) < (u32)t)) {}
    }

    // ---- batch-load the full 32KB h slice: 32 x 16B per lane ----
    // fragment kk: block g' = kk*2 + (hq>>1), offset c*16 + (hq&1)*8
    u32x4 af[32];
    {
      const u16* bs = hbuf + ((size_t)t * 4 + w) * 16384 +
                      (hq >> 1) * 256 + c * 16 + (hq & 1) * 8;
#pragma unroll
      for (int j = 0; j < 8; ++j) {
        const u16* ap = bs + j * 2048;            // +4 blocks per group
        af[j * 4 + 0] = ld16_sc<0>(ap);
        af[j * 4 + 1] = ld16_sc<1024>(ap);
        af[j * 4 + 2] = ld16_sc<2048>(ap);
        af[j * 4 + 3] = ld16_sc<3072>(ap);
      }
    }

    f32x4 acc[3] = {};
#pragma unroll
    for (int ph = 0; ph < 4; ++ph) {
      if (ph == 0)      asm volatile("s_waitcnt vmcnt(24)" ::: "memory");
      else if (ph == 1) asm volatile("s_waitcnt vmcnt(16)" ::: "memory");
      else if (ph == 2) asm volatile("s_waitcnt vmcnt(8)" ::: "memory");
      else              asm volatile("s_waitcnt vmcnt(0)" ::: "memory");
      __builtin_amdgcn_sched_barrier(0);
#pragma unroll
      for (int q = 0; q < 8; ++q) {
        const int kk = ph * 8 + q;
        const bf16x8 a = __builtin_bit_cast(bf16x8, af[kk]);
        const u32x4 b0 = *(const u32x4*)(whs + (kk * 3 + 0) * 512 + lane * 8);
        const u32x4 b1 = *(const u32x4*)(whs + (kk * 3 + 1) * 512 + lane * 8);
        const u32x4 b2 = *(const u32x4*)(whs + (kk * 3 + 2) * 512 + lane * 8);
        acc[0] = MFMA16(a, __builtin_bit_cast(bf16x8, b0), acc[0]);
        acc[1] = MFMA16(a, __builtin_bit_cast(bf16x8, b1), acc[1]);
        acc[2] = MFMA16(a, __builtin_bit_cast(bf16x8, b2), acc[2]);
      }
    }

    // ---- gates (this wave holds r,z,n for its rows x its 16 h-cols) ----
#pragma unroll
    for (int i = 0; i < 4; ++i) {
      const float xr = b2f(gxr[i][0]);
      const float xz = b2f(gxr[i][1]);
      const float xn = b2f(gxr[i][2]);
      const float rr = sigm(xr + acc[0][i] + bhv[0]);
      const float zz = sigm(xz + acc[1][i] + bhv[1]);
      const float nn = tanh_fast(xn + rr * (acc[2][i] + bhv[2]));
      const float hnew = (1.0f - zz) * nn + zz * hprev[i];
      hprev[i] = hnew;
      htile[w][(hq * 4 + i) * 16 + c] = f2b(hnew);   // LDS transpose staging
    }

    // next-step gx prefetch rides the publish drain
    if (t < 255) {
      const u16* gp = gx + (size_t)(t + 1) * 64 * 3072 + gcol;
#pragma unroll
      for (int i = 0; i < 4; ++i) {
        const int b = row0 + hq * 4 + i;
        gxr[i][0] = gp[(size_t)b * 3072];
        gxr[i][1] = gp[(size_t)b * 3072 + 1024];
        gxr[i][2] = gp[(size_t)b * 3072 + 2048];
      }
    }

    asm volatile("s_waitcnt lgkmcnt(0)" ::: "memory");  // htile writes done
    __builtin_amdgcn_sched_barrier(0);
    if (lane < 32) {
      const u32x4 hv = *(const u32x4*)(&htile[w][lane * 8]);
      st16_sc(hbuf + ((size_t)(t + 1) * 4 + w) * 16384 + g * 256 + lane * 8, hv);
    }
    asm volatile("s_waitcnt vmcnt(0)" ::: "memory");    // h tile at LLC
    if (lane == 0)
      st4_sc(tags + ((size_t)((t + 1) & 1) * 4 + w) * (64 * 32) + g * 32,
             (u32)(t + 1));
  }
}

// ---------------- host ----------------
extern "C" void kernel_launch(void* const* d_in, const int* in_sizes, int n_in,
                              void* d_out, int out_size, void* d_ws, size_t ws_size,
                              hipStream_t stream) {
  (void)in_sizes; (void)n_in; (void)out_size; (void)ws_size;
  const int* y = (const int*)d_in[0];
  const float* hidden = (const float*)d_in[1];
  const float* emb = (const float*)d_in[2];
  const float* Wx = (const float*)d_in[3];
  const float* Wh = (const float*)d_in[4];
  const float* bx = (const float*)d_in[5];
  const float* bh = (const float*)d_in[6];
  const float* Wout = (const float*)d_in[7];
  const float* bout = (const float*)d_in[8];

  char* p = (char*)d_ws;
  u16* wx_t = (u16*)p; p += (size_t)3072 * 512 * 2;      // Wx^T  [3072][512]
  u16* wh_t = (u16*)p; p += (size_t)3072 * 1024 * 2;     // Wh^T  [3072][1024]
  u16* wo_t = (u16*)p; p += (size_t)512 * 1024 * 2;      // Wout^T[512][1024]
  u16* aemb = (u16*)p; p += (size_t)16384 * 512 * 2;     // gathered emb bf16
  u16* gx   = (u16*)p; p += (size_t)16384 * 3072 * 2;    // t-major gx
  u16* hbuf = (u16*)p; p += (size_t)257 * 4 * 64 * 256 * 2; // h slots 0..256
  u32* tags = (u32*)p;                                    // [2][4][64][32]

  hipMemsetAsync(tags, 0, 2 * 4 * 64 * 32 * sizeof(u32), stream);
  transpose_cvt<<<dim3(96, 16), dim3(32, 8), 0, stream>>>(Wx, wx_t, 512, 3072);
  transpose_cvt<<<dim3(96, 32), dim3(32, 8), 0, stream>>>(Wh, wh_t, 1024, 3072);
  transpose_cvt<<<dim3(16, 32), dim3(32, 8), 0, stream>>>(Wout, wo_t, 1024, 512);
  gather_cast<<<dim3(8192), dim3(256), 0, stream>>>(y, emb, aemb);
  cast_h0_blocked<<<dim3(256), dim3(256), 0, stream>>>(hidden, hbuf);

  // gx = emb @ Wx + bx   (M=16384, N=3072, K=512)
  gemm_bt<0, 0><<<dim3(24, 128), dim3(256), 0, stream>>>(aemb, wx_t, bx, (void*)gx,
                                                         16384, 3072, 512);
  // GRU scan (64 WGs x 4 independent full-K waves, fresh-slot exchange)
  scan_kernel<<<dim3(64), dim3(256), 0, stream>>>(wh_t, bh, hidden, gx,
                                                  hbuf, tags);
  // logits = tanh(h_1..h_256 @ Wout + bout)  (M=16384, N=512, K=1024)
  gemm_bt<1, 1><<<dim3(4, 128), dim3(256), 0, stream>>>(hbuf, wo_t, bout,
                                                        d_out, 16384, 512, 1024);
}

// Round 10
// 998.332 us; speedup vs baseline: 1.3626x; 1.3626x over previous
//
#include <hip/hip_runtime.h>
#include <stdint.h>

// Problem constants: V=32000, B=64, T=256, D=512, H=1024
typedef unsigned short u16;
typedef unsigned int u32;
typedef __attribute__((ext_vector_type(4))) unsigned int u32x4;
typedef __attribute__((ext_vector_type(4))) float f32x4;
typedef __attribute__((ext_vector_type(8))) __bf16 bf16x8;

#define MFMA16(a, b, c) __builtin_amdgcn_mfma_f32_16x16x32_bf16((a), (b), (c), 0, 0, 0)

__device__ __forceinline__ u16 f2b(float f) {
  union { float f; unsigned u; } v; v.f = f;
  unsigned r = v.u + 0x7FFFu + ((v.u >> 16) & 1u);
  return (u16)(r >> 16);
}
__device__ __forceinline__ float b2f(u16 h) {
  union { unsigned u; float f; } v; v.u = ((unsigned)h) << 16;
  return v.f;
}
__device__ __forceinline__ float sigm(float x) { return 1.0f / (1.0f + __expf(-x)); }
__device__ __forceinline__ float tanh_fast(float x) {
  x = fminf(fmaxf(x, -15.0f), 15.0f);
  float t = __expf(2.0f * x);
  return (t - 1.0f) / (t + 1.0f);
}

// ---- LLC write-through / bypass helpers ----
template <int OFF>
__device__ __forceinline__ u32x4 ld16_sc(const void* p) {
  u32x4 r;
  asm volatile("global_load_dwordx4 %0, %1, off offset:%2 sc0 sc1"
               : "=v"(r) : "v"(p), "i"(OFF));
  return r;
}
__device__ __forceinline__ void st16_sc(void* p, u32x4 v) {
  asm volatile("global_store_dwordx4 %0, %1, off sc0 sc1"
               :: "v"(p), "v"(v) : "memory");
}
__device__ __forceinline__ void st4_sc(u32* p, u32 v) {
  asm volatile("global_store_dword %0, %1, off sc0 sc1"
               :: "v"(p), "v"(v) : "memory");
}

// ---------------- prep kernels ----------------

// src[R][C] f32 -> dst[C][R] bf16 (B^T layout for GEMM / scan)
__global__ void transpose_cvt(const float* __restrict__ src, u16* __restrict__ dst,
                              int R, int C) {
  __shared__ float tile[32][33];
  const int c0 = blockIdx.x * 32, r0 = blockIdx.y * 32;
  const int tx = threadIdx.x, ty = threadIdx.y;
  for (int i = ty; i < 32; i += 8)
    tile[i][tx] = src[(size_t)(r0 + i) * C + (c0 + tx)];
  __syncthreads();
  for (int i = ty; i < 32; i += 8)
    dst[(size_t)(c0 + i) * R + (r0 + tx)] = f2b(tile[tx][i]);
}

// A_emb[m][0:512] = bf16(emb_table[y[m]][:]) ; m = b*T + t (y flat order)
__global__ void gather_cast(const int* __restrict__ y, const float* __restrict__ tab,
                            u16* __restrict__ A) {
  const int idx = blockIdx.x * 256 + threadIdx.x;
  const int m = idx >> 7;
  const int d0 = (idx & 127) << 2;
  const float4 v = *reinterpret_cast<const float4*>(tab + (size_t)y[m] * 512 + d0);
  ushort4 o;
  o.x = f2b(v.x); o.y = f2b(v.y); o.z = f2b(v.z); o.w = f2b(v.w);
  *reinterpret_cast<ushort4*>(A + (size_t)m * 512 + d0) = o;
}

// hidden[64][1024] f32 -> blocked slot 0: [r][g][ii][j], b=r*16+ii, n=g*16+j
__global__ void cast_h0_blocked(const float* __restrict__ h, u16* __restrict__ dst) {
  const int i = blockIdx.x * 256 + threadIdx.x;   // 65536 threads
  const int b = i >> 10, n = i & 1023;
  const int r = b >> 4, ii = b & 15, g = n >> 4, j = n & 15;
  dst[((size_t)r * 64 + g) * 256 + ii * 16 + j] = f2b(h[(size_t)b * 1024 + n]);
}

// ---------------- GEMM: C[m][n] = A[m][K] * Bt[n][K]^T + bias ----------------
// ALAYOUT 0: A row-major [M][K]. ALAYOUT 1: A = hbuf blocked
//   [slot][r][g'][16][16], row m -> slot (m>>6)+1, r=(m>>4)&3, ii=m&15.
template <int EPI, int ALAYOUT>
__global__ __launch_bounds__(256, 2) void gemm_bt(
    const u16* __restrict__ A, const u16* __restrict__ Bt,
    const float* __restrict__ bias, void* __restrict__ Cout,
    int M, int N, int K) {
  __shared__ u16 As[4096], Bs[4096];
  const int tid = threadIdx.x, lane = tid & 63, w = tid >> 6;
  const int wm = w >> 1, wn = w & 1, c = lane & 15, hq = lane >> 4;
  const int m0 = blockIdx.y * 128, n0 = blockIdx.x * 128;
  f32x4 acc[4][4] = {};

  const int slot0 = tid, slot1 = 256 + tid;
  const int r0_ = slot0 >> 2, ko0 = (slot0 & 3) << 3;
  const int r1_ = slot1 >> 2, ko1 = (slot1 & 3) << 3;

  for (int k0 = 0; k0 < K; k0 += 32) {
    u32x4 a0, a1;
    if (ALAYOUT == 0) {
      a0 = *(const u32x4*)(A + (size_t)(m0 + r0_) * K + k0 + ko0);
      a1 = *(const u32x4*)(A + (size_t)(m0 + r1_) * K + k0 + ko1);
    } else {
      const int ma = m0 + r0_, ka = k0 + ko0, mb = m0 + r1_, kb = k0 + ko1;
      a0 = *(const u32x4*)(A + ((((size_t)(ma >> 6) + 1) * 4 + ((ma >> 4) & 3)) * 64 +
                                (ka >> 4)) * 256 + (ma & 15) * 16 + (ka & 15));
      a1 = *(const u32x4*)(A + ((((size_t)(mb >> 6) + 1) * 4 + ((mb >> 4) & 3)) * 64 +
                                (kb >> 4)) * 256 + (mb & 15) * 16 + (kb & 15));
    }
    const u32x4 b0 = *(const u32x4*)(Bt + (size_t)(n0 + r0_) * K + k0 + ko0);
    const u32x4 b1 = *(const u32x4*)(Bt + (size_t)(n0 + r1_) * K + k0 + ko1);
    __syncthreads();
    *(u32x4*)(As + r0_ * 32 + ko0) = a0;
    *(u32x4*)(As + r1_ * 32 + ko1) = a1;
    *(u32x4*)(Bs + r0_ * 32 + ko0) = b0;
    *(u32x4*)(Bs + r1_ * 32 + ko1) = b1;
    __syncthreads();
    u32x4 af[4], bf[4];
#pragma unroll
    for (int i = 0; i < 4; ++i) {
      af[i] = *(const u32x4*)(As + (wm * 64 + i * 16 + c) * 32 + hq * 8);
      bf[i] = *(const u32x4*)(Bs + (wn * 64 + i * 16 + c) * 32 + hq * 8);
    }
#pragma unroll
    for (int mi = 0; mi < 4; ++mi)
#pragma unroll
      for (int ni = 0; ni < 4; ++ni)
        acc[mi][ni] = MFMA16(__builtin_bit_cast(bf16x8, af[mi]),
                             __builtin_bit_cast(bf16x8, bf[ni]), acc[mi][ni]);
  }

#pragma unroll
  for (int ni = 0; ni < 4; ++ni) {
    const int col = n0 + wn * 64 + ni * 16 + c;
    const float bv = bias[col];
#pragma unroll
    for (int mi = 0; mi < 4; ++mi) {
#pragma unroll
      for (int i = 0; i < 4; ++i) {
        const int m = m0 + wm * 64 + mi * 16 + hq * 4 + i;
        const float v = acc[mi][ni][i] + bv;
        if (EPI == 0) {
          const int dr = (m & 255) * 64 + (m >> 8);       // -> [t*64+b][3072]
          ((u16*)Cout)[(size_t)dr * N + col] = f2b(v);
        } else {
          const int dr = (m & 63) * 256 + (m >> 6);       // -> [b*256+t][512]
          ((float*)Cout)[(size_t)dr * N + col] = tanh_fast(v);
        }
      }
    }
  }
}

// ---------------- persistent GRU scan (256 WGs x ONE wave each) -------------
// WG = (g, r): g = col-group (16 h-cols), r = row-class (16 rows). The single
// 64-lane wave owns the FULL K=1024 pipeline for its 16x16 output tile:
// pipelined poll of 64 tags (1/lane) -> batch-load 32KB h slice (sc-bypass,
// staged vmcnt so MFMAs overlap the load tail) -> 96 MFMAs -> gates in-wave
// -> LDS transpose -> 512B burst store -> minimal drain -> tag publish.
// ZERO barriers in the loop; no k-split reduction; waves fully independent.
// Per-CU h-load stays 32KB/step (R7's working ratio) spread over 256 CUs.
// hbuf slots are FRESH per step (no WAR); tags parity + monotonic.
__global__ __launch_bounds__(64, 1) void scan_kernel(
    const u16* __restrict__ wh_t,   // [3072][1024] bf16 (Wh^T)
    const float* __restrict__ bh,   // [3072]
    const float* __restrict__ h0,   // [64][1024] f32
    const u16* __restrict__ gx,     // [256*64][3072] bf16, t-major, incl. bx
    u16* __restrict__ hbuf,         // [257][4][64][256] bf16 blocked, fresh/step
    u32* __restrict__ tags) {       // [2][4][64][32] (128B-padded)
  __shared__ u16 whs[96 * 512];               // 96 KB Wh slice, fragment-ordered
  __shared__ __align__(16) u16 htile[256];    // 512B transpose staging
  const int g = blockIdx.x >> 2, r = blockIdx.x & 3;
  const int lane = threadIdx.x;
  const int c = lane & 15, hq = lane >> 4;
  const int gcol = g * 16 + c;
  const int row0 = r * 16;

  // stage Wh slice, fragment-ordered: fb = kk*3+ct, lane-linear 16B
  for (int fb = 0; fb < 96; ++fb) {
    const int kk = fb / 3, ct = fb % 3;
    const int n = ct * 1024 + g * 16 + c;
    const int k = kk * 32 + hq * 8;
    *(u32x4*)(whs + fb * 512 + lane * 8) =
        *(const u32x4*)(wh_t + (size_t)n * 1024 + k);
  }
  float bhv[3], hprev[4];
  u16 gxr[4][3];
#pragma unroll
  for (int ct = 0; ct < 3; ++ct) bhv[ct] = bh[ct * 1024 + gcol];
#pragma unroll
  for (int i = 0; i < 4; ++i)
    hprev[i] = h0[(size_t)(row0 + hq * 4 + i) * 1024 + gcol];
  {
    const u16* gp = gx + gcol;
#pragma unroll
    for (int i = 0; i < 4; ++i) {
      const int b = row0 + hq * 4 + i;
      gxr[i][0] = gp[(size_t)b * 3072];
      gxr[i][1] = gp[(size_t)b * 3072 + 1024];
      gxr[i][2] = gp[(size_t)b * 3072 + 2048];
    }
  }

  for (int t = 0; t < 256; ++t) {
    // ---- pipelined 2-deep poll of all 64 producers (one tag per lane) ----
    if (t > 0) {
      const u32* tp = tags + ((size_t)(t & 1) * 4 + r) * (64 * 32) + lane * 32;
      const u32 tgt = (u32)t;
      u32 v0, v1;
      asm volatile("global_load_dword %0, %1, off sc0 sc1" : "=v"(v0) : "v"(tp));
      asm volatile("global_load_dword %0, %1, off sc0 sc1" : "=v"(v1) : "v"(tp));
      while (true) {
        asm volatile("s_waitcnt vmcnt(1)" : "+v"(v0));
        if (!__ballot(v0 < tgt)) break;
        asm volatile("global_load_dword %0, %1, off sc0 sc1" : "=v"(v0) : "v"(tp));
        asm volatile("s_waitcnt vmcnt(1)" : "+v"(v1));
        if (!__ballot(v1 < tgt)) break;
        asm volatile("global_load_dword %0, %1, off sc0 sc1" : "=v"(v1) : "v"(tp));
      }
      asm volatile("s_waitcnt vmcnt(0)" ::: "memory");  // retire in-flight polls
      __builtin_amdgcn_sched_barrier(0);
    }

    // ---- batch-load the full 32KB h slice: 32 x 16B per lane ----
    u32x4 af[32];
    {
      const u16* bs = hbuf + ((size_t)t * 4 + r) * 16384 +
                      (hq >> 1) * 256 + c * 16 + (hq & 1) * 8;
#pragma unroll
      for (int j = 0; j < 8; ++j) {
        const u16* ap = bs + j * 2048;            // +4 blocks per group
        af[j * 4 + 0] = ld16_sc<0>(ap);
        af[j * 4 + 1] = ld16_sc<1024>(ap);
        af[j * 4 + 2] = ld16_sc<2048>(ap);
        af[j * 4 + 3] = ld16_sc<3072>(ap);
      }
    }

    f32x4 acc[3] = {};
#pragma unroll
    for (int ph = 0; ph < 4; ++ph) {
      if (ph == 0)      asm volatile("s_waitcnt vmcnt(24)" ::: "memory");
      else if (ph == 1) asm volatile("s_waitcnt vmcnt(16)" ::: "memory");
      else if (ph == 2) asm volatile("s_waitcnt vmcnt(8)" ::: "memory");
      else              asm volatile("s_waitcnt vmcnt(0)" ::: "memory");
      __builtin_amdgcn_sched_barrier(0);
#pragma unroll
      for (int q = 0; q < 8; ++q) {
        const int kk = ph * 8 + q;
        const bf16x8 a = __builtin_bit_cast(bf16x8, af[kk]);
        const u32x4 b0 = *(const u32x4*)(whs + (kk * 3 + 0) * 512 + lane * 8);
        const u32x4 b1 = *(const u32x4*)(whs + (kk * 3 + 1) * 512 + lane * 8);
        const u32x4 b2 = *(const u32x4*)(whs + (kk * 3 + 2) * 512 + lane * 8);
        acc[0] = MFMA16(a, __builtin_bit_cast(bf16x8, b0), acc[0]);
        acc[1] = MFMA16(a, __builtin_bit_cast(bf16x8, b1), acc[1]);
        acc[2] = MFMA16(a, __builtin_bit_cast(bf16x8, b2), acc[2]);
      }
    }

    // ---- gates in-wave (acc holds full-K sums; no reduction needed) ----
#pragma unroll
    for (int i = 0; i < 4; ++i) {
      const float xr = b2f(gxr[i][0]);
      const float xz = b2f(gxr[i][1]);
      const float xn = b2f(gxr[i][2]);
      const float rr = sigm(xr + acc[0][i] + bhv[0]);
      const float zz = sigm(xz + acc[1][i] + bhv[1]);
      const float nn = tanh_fast(xn + rr * (acc[2][i] + bhv[2]));
      const float hnew = (1.0f - zz) * nn + zz * hprev[i];
      hprev[i] = hnew;
      htile[(hq * 4 + i) * 16 + c] = f2b(hnew);   // LDS transpose staging
    }

    asm volatile("s_waitcnt lgkmcnt(0)" ::: "memory");  // htile writes done
    __builtin_amdgcn_sched_barrier(0);
    if (lane < 32) {
      const u32x4 hv = *(const u32x4*)(htile + lane * 8);
      st16_sc(hbuf + ((size_t)(t + 1) * 4 + r) * 16384 + g * 256 + lane * 8, hv);
    }
    asm volatile("s_waitcnt vmcnt(0)" ::: "memory");    // only the store burst
    if (lane == 0)
      st4_sc(tags + ((size_t)((t + 1) & 1) * 4 + r) * (64 * 32) + g * 32,
             (u32)(t + 1));

    // next-step gx prefetch rides the next poll
    if (t < 255) {
      const u16* gp = gx + (size_t)(t + 1) * 64 * 3072 + gcol;
#pragma unroll
      for (int i = 0; i < 4; ++i) {
        const int b = row0 + hq * 4 + i;
        gxr[i][0] = gp[(size_t)b * 3072];
        gxr[i][1] = gp[(size_t)b * 3072 + 1024];
        gxr[i][2] = gp[(size_t)b * 3072 + 2048];
      }
    }
  }
}

// ---------------- host ----------------
extern "C" void kernel_launch(void* const* d_in, const int* in_sizes, int n_in,
                              void* d_out, int out_size, void* d_ws, size_t ws_size,
                              hipStream_t stream) {
  (void)in_sizes; (void)n_in; (void)out_size; (void)ws_size;
  const int* y = (const int*)d_in[0];
  const float* hidden = (const float*)d_in[1];
  const float* emb = (const float*)d_in[2];
  const float* Wx = (const float*)d_in[3];
  const float* Wh = (const float*)d_in[4];
  const float* bx = (const float*)d_in[5];
  const float* bh = (const float*)d_in[6];
  const float* Wout = (const float*)d_in[7];
  const float* bout = (const float*)d_in[8];

  char* p = (char*)d_ws;
  u16* wx_t = (u16*)p; p += (size_t)3072 * 512 * 2;      // Wx^T  [3072][512]
  u16* wh_t = (u16*)p; p += (size_t)3072 * 1024 * 2;     // Wh^T  [3072][1024]
  u16* wo_t = (u16*)p; p += (size_t)512 * 1024 * 2;      // Wout^T[512][1024]
  u16* aemb = (u16*)p; p += (size_t)16384 * 512 * 2;     // gathered emb bf16
  u16* gx   = (u16*)p; p += (size_t)16384 * 3072 * 2;    // t-major gx
  u16* hbuf = (u16*)p; p += (size_t)257 * 4 * 64 * 256 * 2; // h slots 0..256
  u32* tags = (u32*)p;                                    // [2][4][64][32]

  hipMemsetAsync(tags, 0, 2 * 4 * 64 * 32 * sizeof(u32), stream);
  transpose_cvt<<<dim3(96, 16), dim3(32, 8), 0, stream>>>(Wx, wx_t, 512, 3072);
  transpose_cvt<<<dim3(96, 32), dim3(32, 8), 0, stream>>>(Wh, wh_t, 1024, 3072);
  transpose_cvt<<<dim3(16, 32), dim3(32, 8), 0, stream>>>(Wout, wo_t, 1024, 512);
  gather_cast<<<dim3(8192), dim3(256), 0, stream>>>(y, emb, aemb);
  cast_h0_blocked<<<dim3(256), dim3(256), 0, stream>>>(hidden, hbuf);

  // gx = emb @ Wx + bx   (M=16384, N=3072, K=512)
  gemm_bt<0, 0><<<dim3(24, 128), dim3(256), 0, stream>>>(aemb, wx_t, bx, (void*)gx,
                                                         16384, 3072, 512);
  // GRU scan (256 WGs x one independent full-K wave each)
  scan_kernel<<<dim3(256), dim3(64), 0, stream>>>(wh_t, bh, hidden, gx,
                                                  hbuf, tags);
  // logits = tanh(h_1..h_256 @ Wout + bout)  (M=16384, N=512, K=1024)
  gemm_bt<1, 1><<<dim3(4, 128), dim3(256), 0, stream>>>(hbuf, wo_t, bout,
                                                        d_out, 16384, 512, 1024);
}

// Round 11
// 870.812 us; speedup vs baseline: 1.5621x; 1.1464x over previous
//
#include <hip/hip_runtime.h>
#include <stdint.h>

// Problem constants: V=32000, B=64, T=256, D=512, H=1024
typedef unsigned short u16;
typedef unsigned int u32;
typedef __attribute__((ext_vector_type(4))) unsigned int u32x4;
typedef __attribute__((ext_vector_type(4))) float f32x4;
typedef __attribute__((ext_vector_type(8))) __bf16 bf16x8;

#define MFMA16(a, b, c) __builtin_amdgcn_mfma_f32_16x16x32_bf16((a), (b), (c), 0, 0, 0)

__device__ __forceinline__ u16 f2b(float f) {
  union { float f; unsigned u; } v; v.f = f;
  unsigned r = v.u + 0x7FFFu + ((v.u >> 16) & 1u);
  return (u16)(r >> 16);
}
__device__ __forceinline__ float b2f(u16 h) {
  union { unsigned u; float f; } v; v.u = ((unsigned)h) << 16;
  return v.f;
}
__device__ __forceinline__ float sigm(float x) { return 1.0f / (1.0f + __expf(-x)); }
__device__ __forceinline__ float tanh_fast(float x) {
  x = fminf(fmaxf(x, -15.0f), 15.0f);
  float t = __expf(2.0f * x);
  return (t - 1.0f) / (t + 1.0f);
}

// ---- LLC write-through / bypass helpers ----
template <int OFF>
__device__ __forceinline__ u32x4 ld16_sc(const void* p) {
  u32x4 r;
  asm volatile("global_load_dwordx4 %0, %1, off offset:%2 sc0 sc1"
               : "=v"(r) : "v"(p), "i"(OFF));
  return r;
}
__device__ __forceinline__ void st16_sc(void* p, u32x4 v) {
  asm volatile("global_store_dwordx4 %0, %1, off sc0 sc1"
               :: "v"(p), "v"(v) : "memory");
}
__device__ __forceinline__ void st4_sc(u32* p, u32 v) {
  asm volatile("global_store_dword %0, %1, off sc0 sc1"
               :: "v"(p), "v"(v) : "memory");
}
__device__ __forceinline__ u32 ld4_sc(const u32* p) {
  u32 r;
  asm volatile("global_load_dword %0, %1, off sc0 sc1\n\t"
               "s_waitcnt vmcnt(0)"
               : "=v"(r) : "v"(p) : "memory");
  return r;
}

// async global->LDS, 16B per lane (dst must be wave-uniform base + lane*16)
__device__ __forceinline__ void gld_lds16(const void* g, void* l) {
  __builtin_amdgcn_global_load_lds(
      (const __attribute__((address_space(1))) void*)(g),
      (__attribute__((address_space(3))) void*)(l), 16, 0, 0);
}

// ---------------- fused prep kernel (one launch) ----------------
// blocks [0,1536): Wx^T tiles; [1536,4608): Wh^T; [4608,5120): Wout^T;
// [5120,13312): emb gather+cast; [13312,13568): h0 -> blocked slot 0;
// [13568,13600): zero tags.
__global__ __launch_bounds__(256) void prep_all(
    const float* __restrict__ Wx, const float* __restrict__ Wh,
    const float* __restrict__ Wout, const int* __restrict__ y,
    const float* __restrict__ emb, const float* __restrict__ hidden,
    u16* __restrict__ wx_t, u16* __restrict__ wh_t, u16* __restrict__ wo_t,
    u16* __restrict__ aemb, u16* __restrict__ hbuf, u32* __restrict__ tags) {
  __shared__ float tile[32][33];
  const int b = blockIdx.x, tid = threadIdx.x;
  const int tx = tid & 31, ty = tid >> 5;

  const float* src = nullptr; u16* dst = nullptr; int R = 0, C = 0, tb = 0;
  if (b < 1536)      { src = Wx;   dst = wx_t; R = 512;  C = 3072; tb = b; }
  else if (b < 4608) { src = Wh;   dst = wh_t; R = 1024; C = 3072; tb = b - 1536; }
  else if (b < 5120) { src = Wout; dst = wo_t; R = 1024; C = 512;  tb = b - 4608; }

  if (src) {  // 32x32 transpose-cast tile
    const int xt = C >> 5;
    const int c0 = (tb % xt) * 32, r0 = (tb / xt) * 32;
    for (int i = ty; i < 32; i += 8)
      tile[i][tx] = src[(size_t)(r0 + i) * C + (c0 + tx)];
    __syncthreads();
    for (int i = ty; i < 32; i += 8)
      dst[(size_t)(c0 + i) * R + (r0 + tx)] = f2b(tile[tx][i]);
    return;
  }
  if (b < 13312) {  // gather: A_emb[m][:] = bf16(emb[y[m]][:])
    const int idx = (b - 5120) * 256 + tid;
    const int m = idx >> 7, d0 = (idx & 127) << 2;
    const float4 v = *reinterpret_cast<const float4*>(emb + (size_t)y[m] * 512 + d0);
    ushort4 o;
    o.x = f2b(v.x); o.y = f2b(v.y); o.z = f2b(v.z); o.w = f2b(v.w);
    *reinterpret_cast<ushort4*>(aemb + (size_t)m * 512 + d0) = o;
    return;
  }
  if (b < 13568) {  // h0 f32 -> blocked bf16 slot 0
    const int i = (b - 13312) * 256 + tid;
    const int bb = i >> 10, n = i & 1023;
    const int r = bb >> 4, ii = bb & 15, g = n >> 4, j = n & 15;
    hbuf[((size_t)r * 64 + g) * 256 + ii * 16 + j] = f2b(hidden[(size_t)bb * 1024 + n]);
    return;
  }
  {  // zero tags: [2][4][64][32] u32 = 65536 words
    const int base = ((b - 13568) * 256 + tid) * 8;
#pragma unroll
    for (int q = 0; q < 8; ++q) tags[base + q] = 0;
  }
}

// ---------------- GEMM: C[m][n] = A[m][K] * Bt[n][K]^T + bias ----------------
// Staging via global_load_lds (width 16); As/Bs byte layout is 16*tid (linear).
// ALAYOUT 0: A row-major [M][K]. ALAYOUT 1: A = hbuf blocked
//   [slot][r][g'][16][16], row m -> slot (m>>6)+1, r=(m>>4)&3, ii=m&15.
template <int EPI, int ALAYOUT>
__global__ __launch_bounds__(256, 2) void gemm_bt(
    const u16* __restrict__ A, const u16* __restrict__ Bt,
    const float* __restrict__ bias, void* __restrict__ Cout,
    int M, int N, int K) {
  __shared__ u16 As[4096], Bs[4096];
  const int tid = threadIdx.x, lane = tid & 63, w = tid >> 6;
  const int wm = w >> 1, wn = w & 1, c = lane & 15, hq = lane >> 4;
  const int m0 = blockIdx.y * 128, n0 = blockIdx.x * 128;
  f32x4 acc[4][4] = {};

  const int r0_ = tid >> 2, ko0 = (tid & 3) << 3;
  const int r1_ = (256 + tid) >> 2, ko1 = ((256 + tid) & 3) << 3;

  for (int k0 = 0; k0 < K; k0 += 32) {
    const u16 *ga0, *ga1;
    if (ALAYOUT == 0) {
      ga0 = A + (size_t)(m0 + r0_) * K + k0 + ko0;
      ga1 = A + (size_t)(m0 + r1_) * K + k0 + ko1;
    } else {
      const int ma = m0 + r0_, ka = k0 + ko0, mb = m0 + r1_, kb = k0 + ko1;
      ga0 = A + ((((size_t)(ma >> 6) + 1) * 4 + ((ma >> 4) & 3)) * 64 +
                 (ka >> 4)) * 256 + (ma & 15) * 16 + (ka & 15);
      ga1 = A + ((((size_t)(mb >> 6) + 1) * 4 + ((mb >> 4) & 3)) * 64 +
                 (kb >> 4)) * 256 + (mb & 15) * 16 + (kb & 15);
    }
    const u16* gb0 = Bt + (size_t)(n0 + r0_) * K + k0 + ko0;
    const u16* gb1 = Bt + (size_t)(n0 + r1_) * K + k0 + ko1;
    __syncthreads();  // previous iteration's LDS reads complete
    gld_lds16(ga0, (char*)As + tid * 16);
    gld_lds16(ga1, (char*)As + 4096 + tid * 16);
    gld_lds16(gb0, (char*)Bs + tid * 16);
    gld_lds16(gb1, (char*)Bs + 4096 + tid * 16);
    __syncthreads();  // vmcnt drained at barrier -> tiles ready
    u32x4 af[4], bf[4];
#pragma unroll
    for (int i = 0; i < 4; ++i) {
      af[i] = *(const u32x4*)(As + (wm * 64 + i * 16 + c) * 32 + hq * 8);
      bf[i] = *(const u32x4*)(Bs + (wn * 64 + i * 16 + c) * 32 + hq * 8);
    }
#pragma unroll
    for (int mi = 0; mi < 4; ++mi)
#pragma unroll
      for (int ni = 0; ni < 4; ++ni)
        acc[mi][ni] = MFMA16(__builtin_bit_cast(bf16x8, af[mi]),
                             __builtin_bit_cast(bf16x8, bf[ni]), acc[mi][ni]);
  }

#pragma unroll
  for (int ni = 0; ni < 4; ++ni) {
    const int col = n0 + wn * 64 + ni * 16 + c;
    const float bv = bias[col];
#pragma unroll
    for (int mi = 0; mi < 4; ++mi) {
#pragma unroll
      for (int i = 0; i < 4; ++i) {
        const int m = m0 + wm * 64 + mi * 16 + hq * 4 + i;
        const float v = acc[mi][ni][i] + bv;
        if (EPI == 0) {
          const int dr = (m & 255) * 64 + (m >> 8);       // -> [t*64+b][3072]
          ((u16*)Cout)[(size_t)dr * N + col] = f2b(v);
        } else {
          const int dr = (m & 63) * 256 + (m >> 6);       // -> [b*256+t][512]
          ((float*)Cout)[(size_t)dr * N + col] = tanh_fast(v);
        }
      }
    }
  }
}

// ---------------- persistent GRU scan (R7 structure: 256 WGs x 5 waves) -----
// WG = (g, r): g = col-group (16 h-cols), r = row-class (16 rows).
// Waves s=0..3: k-split compute (poll own 16 tags -> batched af load -> MFMA
// -> export partials to red). Wave s=4: dedicated epilogue wave (combine,
// gates, 512B burst h store, drain, tag publish, gx prefetch).
// hbuf slots FRESH per step (no WAR, GEMM2 reads them directly); tags
// parity + monotonic, 128B-padded, serial bypass poll (proven R5/R7 path).
__global__ __launch_bounds__(320, 1) void scan_kernel(
    const u16* __restrict__ wh_t,   // [3072][1024] bf16 (Wh^T)
    const float* __restrict__ bh,   // [3072]
    const float* __restrict__ h0,   // [64][1024] f32
    const u16* __restrict__ gx,     // [256*64][3072] bf16, t-major, incl. bx
    u16* __restrict__ hbuf,         // [257][4][64][256] bf16 blocked, fresh/step
    u32* __restrict__ tags) {       // [2][4][64][32] (128B-padded)
  __shared__ u16 whs[96 * 512];       // 96 KB Wh slice, fragment-ordered
  __shared__ float red[2][4][3][256]; // 24 KB k-partial exchange, parity dbuf
  __shared__ __align__(16) u16 htile[16][16]; // 512B h tile staging
  const int g = blockIdx.x >> 2, r = blockIdx.x & 3;
  const int tid = threadIdx.x, lane = tid & 63, s = tid >> 6;  // s in 0..4
  const int c = lane & 15, hq = lane >> 4;
  const int gcol = g * 16 + c;
  const int row0 = r * 16;

  // stage Wh slice, fragment-ordered: fb=(ss*8+kk)*3+ct, lane-linear 16B
  for (int fb = s; fb < 96; fb += 5) {
    const int ss = fb / 24, kk = (fb % 24) / 3, ct = fb % 3;
    const int n = ct * 1024 + g * 16 + c;
    const int k = ss * 256 + kk * 32 + hq * 8;
    *(u32x4*)(whs + fb * 512 + lane * 8) =
        *(const u32x4*)(wh_t + (size_t)n * 1024 + k);
  }
  float bhv[3], hprev[4];
  u16 gxr[4][3];
  if (s == 4) {
#pragma unroll
    for (int ct = 0; ct < 3; ++ct) bhv[ct] = bh[ct * 1024 + gcol];
#pragma unroll
    for (int i = 0; i < 4; ++i)
      hprev[i] = h0[(size_t)(row0 + hq * 4 + i) * 1024 + gcol];
    const u16* gp = gx + gcol;
#pragma unroll
    for (int i = 0; i < 4; ++i) {
      const int b = row0 + hq * 4 + i;
      gxr[i][0] = gp[(size_t)b * 3072];
      gxr[i][1] = gp[(size_t)b * 3072 + 1024];
      gxr[i][2] = gp[(size_t)b * 3072 + 2048];
    }
  }
  __syncthreads();

  for (int t = 0; t < 256; ++t) {
    if (s < 4) {
      // ---- poll the 16 producers of this wave's K-slice (lanes 0..15) ----
      if (t > 0 && lane < 16) {
        const u32* tp = tags + (((size_t)(t & 1) * 4 + r) * 64 + s * 16 + lane) * 32;
        while (__ballot(ld4_sc(tp) < (u32)t)) {}
      }

      // ---- batched h-fragment loads from fresh slot t (8 KB slice) ----
      u32x4 af[8];
      {
        const u16* ap0 = hbuf + ((size_t)t * 4 + r) * 16384 +
                         (s * 16 + (hq >> 1)) * 256 + c * 16 + (hq & 1) * 8;
        const u16* ap1 = ap0 + 2048;  // +4 blocks
        af[0] = ld16_sc<0>(ap0);    af[1] = ld16_sc<1024>(ap0);
        af[2] = ld16_sc<2048>(ap0); af[3] = ld16_sc<3072>(ap0);
        af[4] = ld16_sc<0>(ap1);    af[5] = ld16_sc<1024>(ap1);
        af[6] = ld16_sc<2048>(ap1); af[7] = ld16_sc<3072>(ap1);
      }
      asm volatile("s_waitcnt vmcnt(0)" ::: "memory");
      __builtin_amdgcn_sched_barrier(0);

      f32x4 acc[3] = {};
#pragma unroll
      for (int kk = 0; kk < 8; ++kk) {
        const int fb = (s * 8 + kk) * 3;
        const u32x4 b0 = *(const u32x4*)(whs + (fb + 0) * 512 + lane * 8);
        const u32x4 b1 = *(const u32x4*)(whs + (fb + 1) * 512 + lane * 8);
        const u32x4 b2 = *(const u32x4*)(whs + (fb + 2) * 512 + lane * 8);
        const bf16x8 a = __builtin_bit_cast(bf16x8, af[kk]);
        acc[0] = MFMA16(a, __builtin_bit_cast(bf16x8, b0), acc[0]);
        acc[1] = MFMA16(a, __builtin_bit_cast(bf16x8, b1), acc[1]);
        acc[2] = MFMA16(a, __builtin_bit_cast(bf16x8, b2), acc[2]);
      }
#pragma unroll
      for (int ct = 0; ct < 3; ++ct)
        *(f32x4*)&red[t & 1][s][ct][lane * 4] = acc[ct];
    }
    __syncthreads();  // the ONLY per-step sync: red[t] exports complete, and
                      // (transitively via tag-gated loads) all producers of
                      // h_t published before any h_{t+1} store below

    if (s == 4) {
      f32x4 a0 = {}, a1 = {}, a2 = {};
#pragma unroll
      for (int j = 0; j < 4; ++j) {
        a0 += *(const f32x4*)&red[t & 1][j][0][lane * 4];
        a1 += *(const f32x4*)&red[t & 1][j][1][lane * 4];
        a2 += *(const f32x4*)&red[t & 1][j][2][lane * 4];
      }
#pragma unroll
      for (int i = 0; i < 4; ++i) {
        const float xr = b2f(gxr[i][0]);
        const float xz = b2f(gxr[i][1]);
        const float xn = b2f(gxr[i][2]);
        const float rr = sigm(xr + a0[i] + bhv[0]);
        const float zz = sigm(xz + a1[i] + bhv[1]);
        const float nn = tanh_fast(xn + rr * (a2[i] + bhv[2]));
        const float hnew = (1.0f - zz) * nn + zz * hprev[i];
        hprev[i] = hnew;
        htile[hq * 4 + i][c] = f2b(hnew);   // stage 16x16 tile for burst store
      }
      asm volatile("s_waitcnt lgkmcnt(0)" ::: "memory");
      __builtin_amdgcn_sched_barrier(0);
      if (lane < 32) {
        const u32x4 hv = *(const u32x4*)((const u16*)htile + lane * 8);
        st16_sc(hbuf + ((size_t)(t + 1) * 4 + r) * 16384 + g * 256 + lane * 8, hv);
      }
      asm volatile("s_waitcnt vmcnt(0)" ::: "memory");  // h tile at LLC
      if (lane == 0)
        st4_sc(tags + (((size_t)((t + 1) & 1) * 4 + r) * 64 + g) * 32, (u32)(t + 1));
      // off-critical-path: next gx prefetch (hidden under next step's poll)
      if (t < 255) {
        const u16* gp = gx + (size_t)(t + 1) * 64 * 3072 + gcol;
#pragma unroll
        for (int i = 0; i < 4; ++i) {
          const int b = row0 + hq * 4 + i;
          gxr[i][0] = gp[(size_t)b * 3072];
          gxr[i][1] = gp[(size_t)b * 3072 + 1024];
          gxr[i][2] = gp[(size_t)b * 3072 + 2048];
        }
      }
    }
  }
}

// ---------------- host ----------------
extern "C" void kernel_launch(void* const* d_in, const int* in_sizes, int n_in,
                              void* d_out, int out_size, void* d_ws, size_t ws_size,
                              hipStream_t stream) {
  (void)in_sizes; (void)n_in; (void)out_size; (void)ws_size;
  const int* y = (const int*)d_in[0];
  const float* hidden = (const float*)d_in[1];
  const float* emb = (const float*)d_in[2];
  const float* Wx = (const float*)d_in[3];
  const float* Wh = (const float*)d_in[4];
  const float* bx = (const float*)d_in[5];
  const float* bh = (const float*)d_in[6];
  const float* Wout = (const float*)d_in[7];
  const float* bout = (const float*)d_in[8];

  char* p = (char*)d_ws;
  u16* wx_t = (u16*)p; p += (size_t)3072 * 512 * 2;      // Wx^T  [3072][512]
  u16* wh_t = (u16*)p; p += (size_t)3072 * 1024 * 2;     // Wh^T  [3072][1024]
  u16* wo_t = (u16*)p; p += (size_t)512 * 1024 * 2;      // Wout^T[512][1024]
  u16* aemb = (u16*)p; p += (size_t)16384 * 512 * 2;     // gathered emb bf16
  u16* gx   = (u16*)p; p += (size_t)16384 * 3072 * 2;    // t-major gx
  u16* hbuf = (u16*)p; p += (size_t)257 * 4 * 64 * 256 * 2; // h slots 0..256
  u32* tags = (u32*)p;                                    // [2][4][64][32]

  // ONE fused prep launch: 3 transposes + gather + h0-cast + tag-zero
  prep_all<<<dim3(13600), dim3(256), 0, stream>>>(Wx, Wh, Wout, y, emb, hidden,
                                                  wx_t, wh_t, wo_t, aemb, hbuf,
                                                  tags);
  // gx = emb @ Wx + bx   (M=16384, N=3072, K=512)
  gemm_bt<0, 0><<<dim3(24, 128), dim3(256), 0, stream>>>(aemb, wx_t, bx, (void*)gx,
                                                         16384, 3072, 512);
  // GRU scan (R7 structure, fresh-slot exchange)
  scan_kernel<<<dim3(256), dim3(320), 0, stream>>>(wh_t, bh, hidden, gx,
                                                   hbuf, tags);
  // logits = tanh(h_1..h_256 @ Wout + bout)  (M=16384, N=512, K=1024)
  gemm_bt<1, 1><<<dim3(4, 128), dim3(256), 0, stream>>>(hbuf, wo_t, bout,
                                                        d_out, 16384, 512, 1024);
}